// Round 13
// baseline (124.509 us; speedup 1.0000x reference)
//
#include <hip/hip_runtime.h>
#include <hip/hip_bf16.h>

// MeanPooling: out[b,e,d] = (sum_l map[b,e,l]*doc[b,l,d]) / lens[b,e]
// B=16, E=256, L=4096 (=K), D=512. fp32 in/out, bf16 MFMA inside.
//
// R13 = R11 (BM=BN=256, 268MB logical, KSPLIT=8, grid 256 = 1 block/CU,
// PASSING) + depth-2 counted-vmcnt pipeline (R10 skeleton) +
// __launch_bounds__(512,2). R12's crash: bounds (512,4) capped VGPR at 128
// < ~220 live -> spill around asm-volatile load dests -> abort. 2 blocks/CU
// is structurally impossible at 256^2 (acc alone = 128 VGPR), so target the
// R8-measured 12 B/cy/CU regime (8-wave, depth-2, counted vmcnt, 1 blk/CU):
// 268MB / (256CU x 12B/cy x 2.1GHz) ~= 41us vs R10's 63.9 at 536MB.
//
// Layouts/staging/swizzles/epilogue: R11 verbatim (verified). Loop: R10/R12
// skeleton (race-audited: barriers separate all cross-wave LDS write/read;
// vmcnt(8) = the other reg-set's 8 loads stay in flight; drain only at exit).

#define NB 16
#define NE 256
#define NL 4096
#define ND 512
#define KSPLIT 8
#define KPW (NL / KSPLIT)   // 512 per block
#define BK 32
#define NT (KPW / BK)       // 16 k-steps

using f32x4  = __attribute__((ext_vector_type(4))) float;
using u32x2  = __attribute__((ext_vector_type(2))) unsigned;
using u32x4  = __attribute__((ext_vector_type(4))) unsigned;
using bf16x8 = __attribute__((ext_vector_type(8))) short;

static __device__ __forceinline__ unsigned bfbits(float x) {
  return (unsigned)__builtin_bit_cast(unsigned short, (__bf16)x);  // RNE
}
static __device__ __forceinline__ unsigned lds_u32(const void* p) {
  return (unsigned)(size_t)(const __attribute__((address_space(3))) void*)p;
}

#define GLOADX4(DST, PTR) \
  asm volatile("global_load_dwordx4 %0, %1, off" : "=v"(DST) : "v"(PTR))
#define DSW64(ADDR, D, OFF) \
  asm volatile("ds_write_b64 %0, %1 offset:" OFF :: "v"(ADDR), "v"(D) : "memory")
#define DSW128(ADDR, D, OFF) \
  asm volatile("ds_write_b128 %0, %1 offset:" OFF :: "v"(ADDR), "v"(D) : "memory")
#define DSR128(DST, ADDR, OFF) \
  asm volatile("ds_read_b128 %0, %1 offset:" OFF : "=v"(DST) : "v"(ADDR))
#define WAIT_VM(N)  asm volatile("s_waitcnt vmcnt(" #N ")" ::: "memory")
#define WAIT_LGKM() asm volatile("s_waitcnt lgkmcnt(0)" ::: "memory")
#define SB0()       __builtin_amdgcn_sched_barrier(0)

// one k-step's staging: 8 x dwordx4 per thread (role decides addresses)
#define STAGE_ISSUE(RS, T)                                                     \
  do {                                                                         \
    const float* p_ = gthr + (size_t)(T) * tstep;                              \
    GLOADX4(RS[0], p_ + st0[0]); GLOADX4(RS[1], p_ + st0[1]);                  \
    GLOADX4(RS[2], p_ + st0[2]); GLOADX4(RS[3], p_ + st0[3]);                  \
    GLOADX4(RS[4], p_ + st0[4]); GLOADX4(RS[5], p_ + st0[5]);                  \
    GLOADX4(RS[6], p_ + st0[6]); GLOADX4(RS[7], p_ + st0[7]);                  \
  } while (0)

// convert to bf16 and write into LDS buffer (OFFS = "0" or "32768")
#define STAGE_WRITE(RS, OFFS)                                                  \
  do {                                                                         \
    if (isB) {                                                                 \
      _Pragma("unroll") for (int j_ = 0; j_ < 4; ++j_) {                       \
        u32x4 wv_;                                                             \
        _Pragma("unroll") for (int k_ = 0; k_ < 4; ++k_)                       \
            wv_[k_] = bfbits(RS[2 * k_][j_]) | (bfbits(RS[2 * k_ + 1][j_]) << 16); \
        DSW128(wAddr[j_], wv_, OFFS);                                          \
      }                                                                        \
    } else {                                                                   \
      _Pragma("unroll") for (int i_ = 0; i_ < 8; ++i_) {                       \
        u32x2 wv_;                                                             \
        wv_[0] = bfbits(RS[i_][0]) | (bfbits(RS[i_][1]) << 16);                \
        wv_[1] = bfbits(RS[i_][2]) | (bfbits(RS[i_][3]) << 16);                \
        DSW64(wAddr[i_], wv_, OFFS);                                           \
      }                                                                        \
    }                                                                          \
  } while (0)

// 8 A frags + 4 B frags (b128, base regs AB/BB per buffer) + 32 MFMA
#define COMPUTE(AB, BB)                                                        \
  do {                                                                         \
    bf16x8 af_[8], bf_[4];                                                     \
    DSR128(af_[0], AB, "0");    DSR128(af_[1], AB, "1024");                    \
    DSR128(af_[2], AB, "2048"); DSR128(af_[3], AB, "3072");                    \
    DSR128(af_[4], AB, "4096"); DSR128(af_[5], AB, "5120");                    \
    DSR128(af_[6], AB, "6144"); DSR128(af_[7], AB, "7168");                    \
    DSR128(bf_[0], BB, "0");    DSR128(bf_[1], BB, "1024");                    \
    DSR128(bf_[2], BB, "2048"); DSR128(bf_[3], BB, "3072");                    \
    WAIT_LGKM();                                                               \
    SB0();                                                                     \
    __builtin_amdgcn_s_setprio(1);                                             \
    _Pragma("unroll") for (int m_ = 0; m_ < 8; ++m_)                           \
        _Pragma("unroll") for (int n_ = 0; n_ < 4; ++n_)                       \
            acc[m_][n_] = __builtin_amdgcn_mfma_f32_16x16x32_bf16(             \
                af_[m_], bf_[n_], acc[m_][n_], 0, 0, 0);                       \
    __builtin_amdgcn_s_setprio(0);                                             \
    SB0();                                                                     \
  } while (0)

__global__ __launch_bounds__(512, 2) void mp_gemm(const float* __restrict__ doc,
                                                  const float* __restrict__ emap,
                                                  const float* __restrict__ lens,
                                                  float* __restrict__ out) {
  // 2 bufs x (A' [256r][32k] bf16 16KB + B' [256d][32k] bf16 16KB) = 64KB
  __shared__ char smem[2 * 32768];

  int bid = (int)blockIdx.x;
  // XCD swizzle: XCD x owns logical [32x,32x+31] = 2 whole batches.
  int logical = (bid & 7) * 32 + (bid >> 3);
  int b  = logical >> 4;        // 16 batches
  int dt = (logical >> 3) & 1;  // d-tile of 256
  int ks = logical & 7;         // k-split x8; siblings adjacent -> same XCD

  int tid  = (int)threadIdx.x;
  int w    = tid >> 6;
  int wr   = w >> 2;          // wave row 0..1 (128 rows each)
  int wc   = w & 3;           // wave col 0..3 (64 cols each)
  int lane = tid & 63;
  int l15  = lane & 15;
  int g    = lane >> 4;

  unsigned ldsb = lds_u32(smem);
  bool isB = (tid < 256);     // waves 0-3 stage B, waves 4-7 stage A

  // ---- staging addresses (per role, R11 verbatim) ----
  const float* gthr;
  size_t tstep;
  int st0[8];
  unsigned wAddr[8];

  if (isB) {
    // wave o=w owns k-octet o; thread q=tid&63 owns d=4q..4q+3.
    // instr i: full k-row (k=8o+i) x 1KB contiguous d-range.
    int q = tid & 63, o = w;
    gthr = doc + ((size_t)b * NL + ks * KPW + 8 * o) * ND + dt * 256 + 4 * q;
    tstep = (size_t)BK * ND;
#pragma unroll
    for (int i = 0; i < 8; ++i) st0[i] = i * ND;
    // B' write: row d=4q+j, octet o at granule o^((d>>2)&3)=o^(q&3)
#pragma unroll
    for (int j = 0; j < 4; ++j)
      wAddr[j] = ldsb + 16384 + (4 * q + j) * 64 + (((o ^ q) & 3) << 4);
  } else {
    // thread v: rows rowb+32i (rowb=v>>3), k-chunk c=v&7 (16B fp32 = 4k)
    int v = tid - 256;
    int rowb = v >> 3, c = v & 7;
    gthr = emap + (size_t)(b * NE + rowb) * NL + ks * KPW + 4 * c;
    tstep = (size_t)BK;
#pragma unroll
    for (int i = 0; i < 8; ++i) st0[i] = i * 32 * NL;
    // A' write: row r, octet c>>1 at granule (c>>1)^(r&3), 8B parity c&1
#pragma unroll
    for (int i = 0; i < 8; ++i) {
      int r = rowb + 32 * i;
      wAddr[i] = ldsb + r * 64 + ((((c >> 1) ^ r) & 3) << 4) + (c & 1) * 8;
    }
  }

  // ---- fragment read base addrs (m/n strides are imm offsets: +1024) ----
  // A frag m: row = 128wr+16m+l15, octet g at granule g^(row&3); row&3=l15&3
  unsigned aRd0 = ldsb + (128 * wr + l15) * 64 + (((g ^ l15) & 3) << 4);
  unsigned aRd1 = aRd0 + 32768;
  // B frag n: d = 64wc+16n+l15, octet g at granule g^((d>>2)&3)=(l15>>2)&3
  unsigned bRd0 = ldsb + 16384 + (64 * wc + l15) * 64 + (((g ^ (l15 >> 2)) & 3) << 4);
  unsigned bRd1 = bRd0 + 32768;

  f32x4 acc[8][4] = {};
  f32x4 RS0[8], RS1[8];

  // prologue: S0<-tile0, S1<-tile1; buf0 <- S0
  STAGE_ISSUE(RS0, 0);
  SB0();
  STAGE_ISSUE(RS1, 1);
  SB0();
  WAIT_VM(8);                  // tile0's 8 loads landed
  SB0();
  STAGE_WRITE(RS0, "0");

#pragma unroll 1
  for (int t = 0; t < NT; t += 2) {
    int p2 = t + 2 < NT ? t + 2 : NT - 1;  // clamped prefetch (tail-safe)
    int p3 = t + 3 < NT ? t + 3 : NT - 1;
    // even: compute buf0(t); issue S0<-t+2; wait t+1; write buf1 <- S1
    WAIT_LGKM();
    __builtin_amdgcn_s_barrier();
    SB0();
    STAGE_ISSUE(RS0, p2);
    SB0();
    COMPUTE(aRd0, bRd0);
    WAIT_VM(8);
    SB0();
    STAGE_WRITE(RS1, "32768");
    // odd: compute buf1(t+1); issue S1<-t+3; wait t+2; write buf0 <- S0
    WAIT_LGKM();
    __builtin_amdgcn_s_barrier();
    SB0();
    STAGE_ISSUE(RS1, p3);
    SB0();
    COMPUTE(aRd1, bRd1);
    WAIT_VM(8);
    SB0();
    STAGE_WRITE(RS0, "0");
  }

  WAIT_VM(0);   // dangling clamped prefetches must land before regs reused
  SB0();

  // epilogue: divide by lens, atomic-accumulate the k-split partial.
  // C/D frag: row = 128wr + 16m + 4g + i, col = dt*256 + 64wc + 16n + l15.
  const float* lb = lens + b * NE + 128 * wr;
  float* ob = out + (size_t)(b * NE + 128 * wr) * ND + dt * 256 + 64 * wc;
#pragma unroll
  for (int m = 0; m < 8; ++m) {
#pragma unroll
    for (int i = 0; i < 4; ++i) {
      int row = 16 * m + 4 * g + i;
      float inv = 1.0f / lb[row];
#pragma unroll
      for (int n = 0; n < 4; ++n)
        unsafeAtomicAdd(&ob[(size_t)row * ND + 16 * n + l15], acc[m][n][i] * inv);
    }
  }
}

extern "C" void kernel_launch(void* const* d_in, const int* in_sizes, int n_in,
                              void* d_out, int out_size, void* d_ws, size_t ws_size,
                              hipStream_t stream) {
  const float* doc  = (const float*)d_in[0];  // (B, L, D)
  const float* emap = (const float*)d_in[1];  // (B, E, L)
  const float* lens = (const float*)d_in[2];  // (B, E)
  float* out = (float*)d_out;                 // (B, E, D)
  hipMemsetAsync(out, 0, (size_t)NB * NE * ND * sizeof(float), stream);
  hipLaunchKernelGGL(mp_gemm, dim3(256), dim3(512), 0, stream, doc, emap, lens, out);
}

// Round 16
// 92.623 us; speedup vs baseline: 1.3442x; 1.3442x over previous
//
#include <hip/hip_runtime.h>
#include <hip/hip_bf16.h>

// MeanPooling: out[b,e,d] = (sum_l map[b,e,l]*doc[b,l,d]) / lens[b,e]
// B=16, E=256, L=4096 (=K), D=512. fp32 in/out, bf16 MFMA inside.
//
// R16: 256^2 tile (268MB logical, half of R10) with ZERO-register staging:
// global_load_lds stages fp32 straight to LDS (no asm-load-dest registers ->
// the hazard class that crashed R12/R14/R15 is structurally gone; m97/m201
// lineage). bf16 convert happens at frag-read time. fp32-in-LDS also removes
// the B transpose: B' stays [k][d] row-major, B-frags read along k.
//  - Grid 256 = 16b x 2dt x 8ks, 1 block/CU, 8 waves, wave tile 128x64,
//    acc[8][4] = 128 AGPR; arch VGPR ~70 -> no spill at (512,2).
//  - LDS 128KB: 2 bufs x (A' [256r][128B] 32KB + B' [32k][1KB] 32KB).
//  - Content swizzles (source-side pre-permute, linear LDS dest, rule 21):
//    A' row r slot s holds chunk (s-r)&7 (16B chunks); read slot (c+r)&7.
//    B' row k slot s holds chunk (s&48)|((s-4*(k>>3))&15); read slot
//    (c&48)|((c+4g)&15). Both give ~2-way banks on frag reads.
//  - Depth-2, counted vmcnt(8) (8 x 1KB global_load_lds per wave per step),
//    2 barriers/step, clamped tail, single drain at exit.
//  - Split-K x8: memsetAsync + unsafeAtomicAdd (L2-local per XCD swizzle).

#define NB 16
#define NE 256
#define NL 4096
#define ND 512
#define KSPLIT 8
#define KPW (NL / KSPLIT)   // 512 per block
#define BK 32
#define NT (KPW / BK)       // 16 k-steps

using f32x4  = __attribute__((ext_vector_type(4))) float;
using u32x4  = __attribute__((ext_vector_type(4))) unsigned;
using bf16x8 = __attribute__((ext_vector_type(8))) short;

static __device__ __forceinline__ unsigned bfbits(float x) {
  return (unsigned)__builtin_bit_cast(unsigned short, (__bf16)x);  // RNE
}
static __device__ __forceinline__ unsigned lds_u32(const void* p) {
  return (unsigned)(size_t)(const __attribute__((address_space(3))) void*)p;
}

#define DSR32(DST, ADDR, OFF) \
  asm volatile("ds_read_b32 %0, %1 offset:" OFF : "=v"(DST) : "v"(ADDR))
#define DSR128(DST, ADDR) \
  asm volatile("ds_read_b128 %0, %1" : "=v"(DST) : "v"(ADDR))
#define WAIT_VM(N)  asm volatile("s_waitcnt vmcnt(" #N ")" ::: "memory")
#define WAIT_LGKM() asm volatile("s_waitcnt lgkmcnt(0)" ::: "memory")
#define SB0()       __builtin_amdgcn_sched_barrier(0)

#define GLDS16(GP, LOFF)                                                       \
  __builtin_amdgcn_global_load_lds(                                            \
      (const __attribute__((address_space(1))) void*)(GP),                     \
      (__attribute__((address_space(3))) void*)(smem + (LOFF)), 16, 0, 0)

// stage k-step T into buffer at byte offset BS: 4 A-instrs + 4 B-instrs
// per wave, each 1KB (16B/lane). vmcnt += 8.
#define ISSUE(T, BS)                                                           \
  do {                                                                         \
    size_t ta_ = (size_t)(T) * 128;    /* A: 32 floats per step  */            \
    size_t tb_ = (size_t)(T) * 65536;  /* B: 32 rows x 2KB per step */         \
    GLDS16(srcA0 + ta_, (BS) + aDst0); GLDS16(srcA1 + ta_, (BS) + aDst1);      \
    GLDS16(srcA2 + ta_, (BS) + aDst2); GLDS16(srcA3 + ta_, (BS) + aDst3);      \
    GLDS16(srcB0 + tb_, (BS) + bDst0); GLDS16(srcB1 + tb_, (BS) + bDst1);      \
    GLDS16(srcB2 + tb_, (BS) + bDst2); GLDS16(srcB3 + tb_, (BS) + bDst3);      \
  } while (0)

// read frags fp32 from LDS buffer at BS, cvt to bf16, 32 MFMA.
#define COMPUTE(BS)                                                            \
  do {                                                                         \
    bf16x8 bf_[4];                                                             \
    _Pragma("unroll") for (int n_ = 0; n_ < 4; ++n_) {                         \
      float tb_[8];                                                            \
      unsigned ba_ = bRd[n_] + (BS);                                           \
      DSR32(tb_[0], ba_, "0");    DSR32(tb_[1], ba_, "1024");                  \
      DSR32(tb_[2], ba_, "2048"); DSR32(tb_[3], ba_, "3072");                  \
      DSR32(tb_[4], ba_, "4096"); DSR32(tb_[5], ba_, "5120");                  \
      DSR32(tb_[6], ba_, "6144"); DSR32(tb_[7], ba_, "7168");                  \
      WAIT_LGKM();                                                             \
      SB0();                                                                   \
      u32x4 pk_;                                                               \
      _Pragma("unroll") for (int j_ = 0; j_ < 4; ++j_)                         \
          pk_[j_] = bfbits(tb_[2 * j_]) | (bfbits(tb_[2 * j_ + 1]) << 16);     \
      bf_[n_] = __builtin_bit_cast(bf16x8, pk_);                               \
    }                                                                          \
    __builtin_amdgcn_s_setprio(1);                                             \
    _Pragma("unroll") for (int m_ = 0; m_ < 8; ++m_) {                         \
      f32x4 lo_, hi_;                                                          \
      DSR128(lo_, aRd0 + (BS) + m_ * 2048);                                    \
      DSR128(hi_, aRd1 + (BS) + m_ * 2048);                                    \
      WAIT_LGKM();                                                             \
      SB0();                                                                   \
      u32x4 pa_;                                                               \
      pa_[0] = bfbits(lo_[0]) | (bfbits(lo_[1]) << 16);                        \
      pa_[1] = bfbits(lo_[2]) | (bfbits(lo_[3]) << 16);                        \
      pa_[2] = bfbits(hi_[0]) | (bfbits(hi_[1]) << 16);                        \
      pa_[3] = bfbits(hi_[2]) | (bfbits(hi_[3]) << 16);                        \
      bf16x8 af_ = __builtin_bit_cast(bf16x8, pa_);                            \
      acc[m_][0] = __builtin_amdgcn_mfma_f32_16x16x32_bf16(af_, bf_[0], acc[m_][0], 0, 0, 0); \
      acc[m_][1] = __builtin_amdgcn_mfma_f32_16x16x32_bf16(af_, bf_[1], acc[m_][1], 0, 0, 0); \
      acc[m_][2] = __builtin_amdgcn_mfma_f32_16x16x32_bf16(af_, bf_[2], acc[m_][2], 0, 0, 0); \
      acc[m_][3] = __builtin_amdgcn_mfma_f32_16x16x32_bf16(af_, bf_[3], acc[m_][3], 0, 0, 0); \
    }                                                                          \
    __builtin_amdgcn_s_setprio(0);                                             \
    SB0();                                                                     \
  } while (0)

__global__ __launch_bounds__(512, 2) void mp_gemm(const float* __restrict__ doc,
                                                  const float* __restrict__ emap,
                                                  const float* __restrict__ lens,
                                                  float* __restrict__ out) {
  // 128KB: 2 bufs (stride 65536) x { A' fp32 [256r][128B] ; B' fp32 [32k][1KB] at +32768 }
  __shared__ char smem[2 * 65536];

  int bid = (int)blockIdx.x;
  // XCD swizzle: XCD x owns logical [32x,32x+31] = 2 whole batches.
  int logical = (bid & 7) * 32 + (bid >> 3);
  int b  = logical >> 4;        // 16 batches
  int dt = (logical >> 3) & 1;  // d-tile of 256
  int ks = logical & 7;         // k-split x8; siblings adjacent -> same XCD

  int tid  = (int)threadIdx.x;
  int w    = tid >> 6;
  int wr   = w >> 2;          // wave row 0..1 (128 rows each)
  int wc   = w & 3;           // wave col 0..3 (64 cols each)
  int lane = tid & 63;
  int l15  = lane & 15;
  int g    = lane >> 4;

  unsigned ldsb = lds_u32(smem);

  // ---- staging sources (per-lane, content-swizzled) + LDS dests (uniform) ----
  // A instr i: rows r0=32w+8i..+7; lane -> row r0+(lane>>3), slot lane&7;
  //            slot s of row r holds chunk (s-r)&7 of the row's 128B k-slice.
  const char* srcA0; const char* srcA1; const char* srcA2; const char* srcA3;
  unsigned aDst0, aDst1, aDst2, aDst3;
  {
    const char* sa[4]; unsigned ad[4];
#pragma unroll
    for (int i = 0; i < 4; ++i) {
      int r0 = 32 * w + 8 * i;
      int r  = r0 + (lane >> 3);
      int cg = ((lane & 7) - r) & 7;
      sa[i] = (const char*)(emap + (size_t)(b * NE + r) * NL + ks * KPW) + cg * 16;
      ad[i] = (unsigned)(r0 * 128);
    }
    srcA0 = sa[0]; srcA1 = sa[1]; srcA2 = sa[2]; srcA3 = sa[3];
    aDst0 = ad[0]; aDst1 = ad[1]; aDst2 = ad[2]; aDst3 = ad[3];
  }
  // B instr i: k-row kr=4w+i (1KB of d); lane -> slot lane; slot s holds
  //            chunk (s&48)|((s-4*(kr>>3))&15).
  const char* srcB0; const char* srcB1; const char* srcB2; const char* srcB3;
  unsigned bDst0, bDst1, bDst2, bDst3;
  {
    const char* sb[4]; unsigned bd[4];
#pragma unroll
    for (int i = 0; i < 4; ++i) {
      int kr = 4 * w + i;
      int cg = (lane & 48) | ((lane - 4 * (kr >> 3)) & 15);
      sb[i] = (const char*)(doc + ((size_t)b * NL + ks * KPW + kr) * ND + dt * 256) + cg * 16;
      bd[i] = (unsigned)(32768 + kr * 1024);
    }
    srcB0 = sb[0]; srcB1 = sb[1]; srcB2 = sb[2]; srcB3 = sb[3];
    bDst0 = bd[0]; bDst1 = bd[1]; bDst2 = bd[2]; bDst3 = bd[3];
  }

  // ---- fragment read bases ----
  // A frag m (row 128wr+16m+l15, k=8g..8g+7): slot h -> (2g+h+l15)&7; +m*2048.
  unsigned aRd0 = ldsb + (unsigned)((128 * wr + l15) * 128 + (((2 * g + 0 + l15) & 7) << 4));
  unsigned aRd1 = ldsb + (unsigned)((128 * wr + l15) * 128 + (((2 * g + 1 + l15) & 7) << 4));
  // B frag n (d = 64wc+16n+l15, k=8g+j): row 8g+j (+j*1024 imm), slot
  // 16wc + ((4n + (l15>>2) + 4g)&15), dword l15&3.
  unsigned bRd[4];
#pragma unroll
  for (int n = 0; n < 4; ++n)
    bRd[n] = ldsb + (unsigned)(32768 + 8 * g * 1024 +
             (16 * wc + ((4 * n + (l15 >> 2) + 4 * g) & 15)) * 16 + (l15 & 3) * 4);

  f32x4 acc[8][4] = {};

  // prologue: tile0 -> buf0, tile1 -> buf1 (16 outstanding per wave)
  ISSUE(0, 0);
  SB0();
  ISSUE(1, 65536);
  SB0();

#pragma unroll 1
  for (int t = 0; t < NT; t += 2) {
    int p0 = t + 2 < NT ? t + 2 : NT - 1;  // clamped (tail-safe; dups benign)
    int p1 = t + 3 < NT ? t + 3 : NT - 1;
    // even: consume buf0 (tile t), refill buf0 <- t+2
    WAIT_VM(8);                       // this wave's buf0 loads landed
    SB0();
    __builtin_amdgcn_s_barrier();     // all waves' buf0 loads landed
    SB0();
    COMPUTE(0);
    __builtin_amdgcn_s_barrier();     // all waves done reading buf0
    SB0();
    ISSUE(p0, 0);
    SB0();
    // odd: consume buf1 (tile t+1), refill buf1 <- t+3
    WAIT_VM(8);
    SB0();
    __builtin_amdgcn_s_barrier();
    SB0();
    COMPUTE(65536);
    __builtin_amdgcn_s_barrier();
    SB0();
    ISSUE(p1, 65536);
    SB0();
  }

  WAIT_VM(0);   // drain dangling clamped prefetches
  SB0();

  // epilogue (R11-verified): divide by lens, atomic-add k-split partial.
  // C/D frag: row = 128wr + 16m + 4g + i, col = dt*256 + 64wc + 16n + l15.
  const float* lb = lens + b * NE + 128 * wr;
  float* ob = out + (size_t)(b * NE + 128 * wr) * ND + dt * 256 + 64 * wc;
#pragma unroll
  for (int m = 0; m < 8; ++m) {
#pragma unroll
    for (int i = 0; i < 4; ++i) {
      int row = 16 * m + 4 * g + i;
      float inv = 1.0f / lb[row];
#pragma unroll
      for (int n = 0; n < 4; ++n)
        unsafeAtomicAdd(&ob[(size_t)row * ND + 16 * n + l15], acc[m][n][i] * inv);
    }
  }
}

extern "C" void kernel_launch(void* const* d_in, const int* in_sizes, int n_in,
                              void* d_out, int out_size, void* d_ws, size_t ws_size,
                              hipStream_t stream) {
  const float* doc  = (const float*)d_in[0];  // (B, L, D)
  const float* emap = (const float*)d_in[1];  // (B, E, L)
  const float* lens = (const float*)d_in[2];  // (B, E)
  float* out = (float*)d_out;                 // (B, E, D)
  hipMemsetAsync(out, 0, (size_t)NB * NE * ND * sizeof(float), stream);
  hipLaunchKernelGGL(mp_gemm, dim3(256), dim3(512), 0, stream, doc, emap, lens, out);
}